// Round 1
// baseline (32.655 us; speedup 1.0000x reference)
//
#include <hip/hip_runtime.h>

// GCNCountry: reference output = ((leaky(leaky(adj@(x@Wgc)+bgc) @ W1 + b1) * dropmask) @ W2 + b2)[0]
// -> depends ONLY on row 0 of every intermediate. Collapse to vector chain:
//    v = adj[0,:] @ x            (8192x512 reads, 16 MB -- the only big kernel)
//    h0 = v @ Wgc                (2 MB)
//    h1 = leaky(h0+bgc) @ W1     (2 MB)
//    out = (dropout(leaky(h1+b1)) @ W2[:,0]) + b2
// ~146 GFLOP reference collapses to ~10 MFLOP + ~20 MB traffic.

constexpr int N_NODES = 8192;
constexpr int N_FEAT  = 512;   // x cols
constexpr int N_HID1  = 1024;
constexpr int N_HID2  = 512;
constexpr float SLOPE = 0.01f;
constexpr float DROP_P = 0.3f;

__device__ __forceinline__ float leaky(float x) { return x >= 0.f ? x : SLOPE * x; }

// ws layout (floats): v[0:512], h0[512:1536], h1[1536:2048]

// K1: v[j] = sum_i adj[0,i] * x[i,j].  256 blocks x 32 rows each; thread t owns cols 2t,2t+1.
__global__ void k1_adjrow_x(const float* __restrict__ x, const float* __restrict__ adj0,
                            float* __restrict__ v) {
    const float2* x2 = reinterpret_cast<const float2*>(x);
    const int t  = threadIdx.x;          // 0..255
    const int r0 = blockIdx.x * 32;
    float ax = 0.f, ay = 0.f;
    #pragma unroll
    for (int r = 0; r < 32; ++r) {
        const int row = r0 + r;
        const float a = adj0[row];                       // adj[0, row]
        const float2 xv = x2[row * (N_FEAT / 2) + t];    // coalesced 8B/lane
        ax = fmaf(a, xv.x, ax);
        ay = fmaf(a, xv.y, ay);
    }
    atomicAdd(&v[2 * t],     ax);
    atomicAdd(&v[2 * t + 1], ay);
}

// K2: h0[j] += sum_{k in chunk} v[k] * Wgc[k,j].  grid (4 j-blocks, 32 k-chunks of 16).
__global__ void k2_v_wgc(const float* __restrict__ v, const float* __restrict__ Wgc,
                         float* __restrict__ h0) {
    const int j  = blockIdx.x * 256 + threadIdx.x;  // 0..1023
    const int k0 = blockIdx.y * 16;
    float acc = 0.f;
    #pragma unroll
    for (int k = 0; k < 16; ++k)
        acc = fmaf(v[k0 + k], Wgc[(k0 + k) * N_HID1 + j], acc);
    atomicAdd(&h0[j], acc);
}

// K3: h1[j] += sum_{k in chunk} leaky(h0[k]+bgc[k]) * W1[k,j].  grid (2, 32 chunks of 32).
// bias+leaky applied on the fly (redundant across j-blocks, trivial cost) -> saves a launch.
__global__ void k3_h0_w1(const float* __restrict__ h0, const float* __restrict__ bgc,
                         const float* __restrict__ W1, float* __restrict__ h1) {
    const int j  = blockIdx.x * 256 + threadIdx.x;  // 0..511
    const int k0 = blockIdx.y * 32;
    float acc = 0.f;
    #pragma unroll
    for (int k = 0; k < 32; ++k) {
        const int kk = k0 + k;
        const float h = leaky(h0[kk] + bgc[kk]);
        acc = fmaf(h, W1[kk * N_HID2 + j], acc);
    }
    atomicAdd(&h1[j], acc);
}

// K4: finalize: bias+leaky+dropout(row0 of drop_u), dot with W2[:,0], add b2 -> out[0].
__global__ void k4_final(const float* __restrict__ h1, const float* __restrict__ b1,
                         const float* __restrict__ W2, const float* __restrict__ b2,
                         const float* __restrict__ du0, float* __restrict__ out) {
    const int j = threadIdx.x;  // 512 threads
    float h = leaky(h1[j] + b1[j]);
    h = (du0[j] >= DROP_P) ? h / (1.0f - DROP_P) : 0.f;
    float term = h * W2[j];     // W2 is [512][1]

    #pragma unroll
    for (int off = 32; off > 0; off >>= 1)
        term += __shfl_down(term, off, 64);

    __shared__ float red[8];
    const int lane = j & 63, wid = j >> 6;
    if (lane == 0) red[wid] = term;
    __syncthreads();
    if (j == 0) {
        float s = 0.f;
        #pragma unroll
        for (int w = 0; w < 8; ++w) s += red[w];
        out[0] = s + b2[0];
    }
}

extern "C" void kernel_launch(void* const* d_in, const int* in_sizes, int n_in,
                              void* d_out, int out_size, void* d_ws, size_t ws_size,
                              hipStream_t stream) {
    const float* x   = (const float*)d_in[0];
    const float* adj = (const float*)d_in[1];  // row 0 = first 8192 floats
    const float* Wgc = (const float*)d_in[2];
    const float* bgc = (const float*)d_in[3];
    const float* W1  = (const float*)d_in[4];
    const float* b1  = (const float*)d_in[5];
    const float* W2  = (const float*)d_in[6];
    const float* b2  = (const float*)d_in[7];
    const float* du  = (const float*)d_in[8];  // row 0 = first 512 floats
    float* out = (float*)d_out;

    float* ws = (float*)d_ws;
    float* v  = ws;
    float* h0 = ws + 512;
    float* h1 = ws + 1536;

    // d_ws is poisoned 0xAA and NOT re-poisoned between replays: zero accumulators every call.
    hipMemsetAsync(d_ws, 0, 2048 * sizeof(float), stream);

    k1_adjrow_x<<<dim3(N_NODES / 32), dim3(256), 0, stream>>>(x, adj, v);
    k2_v_wgc  <<<dim3(4, 32),         dim3(256), 0, stream>>>(v, Wgc, h0);
    k3_h0_w1  <<<dim3(2, 32),         dim3(256), 0, stream>>>(h0, bgc, W1, h1);
    k4_final  <<<dim3(1),             dim3(512), 0, stream>>>(h1, b1, W2, b2, du, out);
}

// Round 2
// 17.552 us; speedup vs baseline: 1.8604x; 1.8604x over previous
//
#include <hip/hip_runtime.h>

// GCNCountry: out = ((leaky(leaky(adj@(x@Wgc)+bgc) @ W1 + b1) * dropmask) @ W2 + b2)[0]
// -> depends ONLY on row 0 of every intermediate. Vector chain:
//    v  = adj[0,:] @ x            (16 MB x-read -- the only big kernel)
//    h0 = v @ Wgc                 (2 MB)
//    h1 = leaky(h0+bgc) @ W1      (2 MB)
//    out = dropout(leaky(h1+b1)) . W2[:,0] + b2
// All stages write PARTIALS (no atomics, no memset dispatch); consumer reduces
// the partials from L2. 4 dispatches total, everything L3-resident.

constexpr int N_FEAT  = 512;
constexpr int N_HID1  = 1024;
constexpr int N_HID2  = 512;
constexpr float SLOPE  = 0.01f;
constexpr float DROP_P = 0.3f;

__device__ __forceinline__ float leaky(float x) { return x >= 0.f ? x : SLOPE * x; }

// ws float layout:
//   v_part  [32][512]   @ 0       (K1 out: 32 row-chunk partials of v)
//   h0_part [16][1024]  @ 16384   (K2 out: 16 k-chunk partials of h0)
//   h1_part [16][512]   @ 32768   (K3 out: 16 k-chunk partials of h1)
constexpr int VP_N  = 32;
constexpr int H0_N  = 16;
constexpr int H1_N  = 16;
constexpr int VP_OFF = 0;
constexpr int H0_OFF = 16384;
constexpr int H1_OFF = 32768;

// K1: v_part[rb][c] = sum_{rows in chunk rb} adj0[row] * x[row][c]
// grid (8 col-stripes of 64, 32 row-chunks of 256), 256 thr.
// Thread (r=tid>>4, f4=tid&15): 16 lanes x float4 = 256B contiguous per row -> full coalescing.
__global__ __launch_bounds__(256) void k1_adjrow_x(const float* __restrict__ x,
                                                   const float* __restrict__ adj0,
                                                   float* __restrict__ vp) {
    const int tid = threadIdx.x;
    const int f4  = tid & 15;
    const int r   = tid >> 4;          // 0..15
    const int c0  = blockIdx.x * 64;   // col stripe
    const int rb  = blockIdx.y;        // row chunk
    const float4* x4 = reinterpret_cast<const float4*>(x);

    float4 acc = {0.f, 0.f, 0.f, 0.f};
    int row = rb * 256 + r;
    #pragma unroll
    for (int it = 0; it < 16; ++it, row += 16) {
        const float  a  = adj0[row];
        const float4 xv = x4[row * (N_FEAT / 4) + (c0 >> 2) + f4];
        acc.x = fmaf(a, xv.x, acc.x);
        acc.y = fmaf(a, xv.y, acc.y);
        acc.z = fmaf(a, xv.z, acc.z);
        acc.w = fmaf(a, xv.w, acc.w);
    }

    __shared__ float4 sm[256];
    sm[tid] = acc;
    __syncthreads();
    #pragma unroll
    for (int off = 128; off >= 16; off >>= 1) {      // reduce over the 16 r-groups
        if (tid < off) {
            float4 o = sm[tid + off];
            sm[tid].x += o.x; sm[tid].y += o.y; sm[tid].z += o.z; sm[tid].w += o.w;
        }
        __syncthreads();
    }
    if (tid < 16)
        reinterpret_cast<float4*>(vp + rb * N_FEAT + c0)[tid] = sm[tid];
}

// K2: h0_part[kc][j] = sum_{k in chunk kc} v[k] * Wgc[k][j];  v reduced from v_part on the fly.
// grid (4 j-blocks, 16 k-chunks of 32), 256 thr.
__global__ __launch_bounds__(256) void k2_v_wgc(const float* __restrict__ vp,
                                                const float* __restrict__ Wgc,
                                                float* __restrict__ h0p) {
    const int j  = blockIdx.x * 256 + threadIdx.x;   // 0..1023
    const int kc = blockIdx.y;
    const int k0 = kc * 32;

    __shared__ float vl[32];
    if (threadIdx.x < 32) {
        float s = 0.f;
        #pragma unroll
        for (int p = 0; p < VP_N; ++p) s += vp[p * N_FEAT + k0 + threadIdx.x];
        vl[threadIdx.x] = s;
    }
    __syncthreads();

    float acc = 0.f;
    #pragma unroll
    for (int k = 0; k < 32; ++k)
        acc = fmaf(vl[k], Wgc[(k0 + k) * N_HID1 + j], acc);
    h0p[kc * N_HID1 + j] = acc;
}

// K3: h1_part[kc][j] = sum_{k in chunk} leaky(h0[k]+bgc[k]) * W1[k][j];  h0 reduced on the fly.
// grid (2 j-blocks, 16 k-chunks of 64), 256 thr.
__global__ __launch_bounds__(256) void k3_h0_w1(const float* __restrict__ h0p,
                                                const float* __restrict__ bgc,
                                                const float* __restrict__ W1,
                                                float* __restrict__ h1p) {
    const int j  = blockIdx.x * 256 + threadIdx.x;   // 0..511
    const int kc = blockIdx.y;
    const int k0 = kc * 64;

    __shared__ float hl[64];
    if (threadIdx.x < 64) {
        const int k = k0 + threadIdx.x;
        float s = bgc[k];
        #pragma unroll
        for (int p = 0; p < H0_N; ++p) s += h0p[p * N_HID1 + k];
        hl[threadIdx.x] = leaky(s);
    }
    __syncthreads();

    float acc = 0.f;
    #pragma unroll
    for (int k = 0; k < 64; ++k)
        acc = fmaf(hl[k], W1[(k0 + k) * N_HID2 + j], acc);
    h1p[kc * N_HID2 + j] = acc;
}

// K4: reduce h1 partials, bias+leaky+dropout(row0 of drop_u), dot W2[:,0], +b2 -> out[0].
__global__ __launch_bounds__(512) void k4_final(const float* __restrict__ h1p,
                                                const float* __restrict__ b1,
                                                const float* __restrict__ W2,
                                                const float* __restrict__ b2,
                                                const float* __restrict__ du0,
                                                float* __restrict__ out) {
    const int j = threadIdx.x;  // 512 threads
    float s = b1[j];
    #pragma unroll
    for (int p = 0; p < H1_N; ++p) s += h1p[p * N_HID2 + j];
    float h = leaky(s);
    h = (du0[j] >= DROP_P) ? h / (1.0f - DROP_P) : 0.f;
    float term = h * W2[j];   // W2 is [512][1]

    #pragma unroll
    for (int off = 32; off; off >>= 1) term += __shfl_down(term, off, 64);

    __shared__ float red[8];
    if ((j & 63) == 0) red[j >> 6] = term;
    __syncthreads();
    if (j == 0) {
        float t = 0.f;
        #pragma unroll
        for (int w = 0; w < 8; ++w) t += red[w];
        out[0] = t + b2[0];
    }
}

extern "C" void kernel_launch(void* const* d_in, const int* in_sizes, int n_in,
                              void* d_out, int out_size, void* d_ws, size_t ws_size,
                              hipStream_t stream) {
    const float* x   = (const float*)d_in[0];
    const float* adj = (const float*)d_in[1];  // row 0 = first 8192 floats
    const float* Wgc = (const float*)d_in[2];
    const float* bgc = (const float*)d_in[3];
    const float* W1  = (const float*)d_in[4];
    const float* b1  = (const float*)d_in[5];
    const float* W2  = (const float*)d_in[6];
    const float* b2  = (const float*)d_in[7];
    const float* du  = (const float*)d_in[8];  // row 0 = first 512 floats
    float* out = (float*)d_out;
    float* ws  = (float*)d_ws;

    // Every ws cell consumed is written earlier in the same call -- no memset,
    // no atomics, deterministic across replays.
    k1_adjrow_x<<<dim3(8, 32), 256, 0, stream>>>(x, adj, ws + VP_OFF);
    k2_v_wgc  <<<dim3(4, 16), 256, 0, stream>>>(ws + VP_OFF, Wgc, ws + H0_OFF);
    k3_h0_w1  <<<dim3(2, 16), 256, 0, stream>>>(ws + H0_OFF, bgc, W1, ws + H1_OFF);
    k4_final  <<<dim3(1),     512, 0, stream>>>(ws + H1_OFF, b1, W2, b2, du, out);
}